// Round 10
// baseline (271.513 us; speedup 1.0000x reference)
//
#include <hip/hip_runtime.h>

// GuidedAttention on MI355X, round 10: k_conv staging rebuilt (per-lane byte
// columns -> conflict-free LDS writes) + P staged in LDS -> coalesced uint4
// global stores (was 64 scattered byte-stores/thread). Other kernels unchanged.
// b=8, n=1024, c=512, H=8, hd=64.
// ws layout (160 MB): [Q bf16 8MB | D f32 256KB overlaid after k_qk]
//                     [K bf16 8MB][V bf16 8MB][Z bf16 8MB]
//                     [S fp8 64MB][P fp8 64MB]

#define DINL __device__ __forceinline__
typedef unsigned short u16;
typedef unsigned int u32;
typedef unsigned long long u64;
typedef short bf16x8 __attribute__((ext_vector_type(8)));
typedef float f32x4 __attribute__((ext_vector_type(4)));
typedef float f32x2 __attribute__((ext_vector_type(2)));

DINL u16 f2bf(float f) {
  u32 u = __float_as_uint(f);
  u += 0x7fffu + ((u >> 16) & 1u);
  return (u16)(u >> 16);
}
DINL float bflo(u32 u) { return __uint_as_float(u << 16); }
DINL float bfhi(u32 u) { return __uint_as_float(u & 0xffff0000u); }
DINL u32 cvtpk_bf16(float lo, float hi) {
  u32 r;
  asm("v_cvt_pk_bf16_f32 %0, %1, %2" : "=v"(r) : "v"(lo), "v"(hi));
  return r;
}
DINL f32x2 up2_lo(u32 w) { return __builtin_amdgcn_cvt_pk_f32_fp8((int)w, false); }
DINL unsigned char f2fp8(float v) {
  return (unsigned char)((u32)__builtin_amdgcn_cvt_pk_fp8_f32(v, v, 0, false) & 0xffu);
}

// ---------- Kernel 1: QKV proj, bf16 MFMA. M=8192, N=1536, K=512 ----------
__global__ __launch_bounds__(256) void k_qkv(const float* __restrict__ x,
                                             const float* __restrict__ w,
                                             u16* __restrict__ Q,
                                             u16* __restrict__ K,
                                             u16* __restrict__ V) {
  __shared__ __align__(16) u16 sA[128 * 64];
  __shared__ __align__(16) u16 sB[128 * 64];
  const int tid = threadIdx.x;
  const int m0 = blockIdx.x * 128, n0 = blockIdx.y * 128;
  const int lane = tid & 63, wid = tid >> 6;
  const int wr = wid >> 1, wc = wid & 1;
  const int l15 = lane & 15, l4 = lane >> 4;
  const int row = tid >> 1, half = tid & 1, xr = row & 7;
  f32x4 acc[4][4] = {};
  for (int k0 = 0; k0 < 512; k0 += 64) {
    __syncthreads();
    {
      const float* ga = &x[(size_t)(m0 + row) * 512 + k0 + half * 32];
      const float* gb = &w[(size_t)(n0 + row) * 512 + k0 + half * 32];
#pragma unroll
      for (int q = 0; q < 4; ++q) {
        int gp = (half * 4 + q) ^ xr;
        float4 a0 = *(const float4*)&ga[q * 8];
        float4 a1 = *(const float4*)&ga[q * 8 + 4];
        uint4 pa;
        pa.x = cvtpk_bf16(a0.x, a0.y); pa.y = cvtpk_bf16(a0.z, a0.w);
        pa.z = cvtpk_bf16(a1.x, a1.y); pa.w = cvtpk_bf16(a1.z, a1.w);
        *(uint4*)&sA[row * 64 + gp * 8] = pa;
        float4 b0 = *(const float4*)&gb[q * 8];
        float4 b1 = *(const float4*)&gb[q * 8 + 4];
        uint4 pb;
        pb.x = cvtpk_bf16(b0.x, b0.y); pb.y = cvtpk_bf16(b0.z, b0.w);
        pb.z = cvtpk_bf16(b1.x, b1.y); pb.w = cvtpk_bf16(b1.z, b1.w);
        *(uint4*)&sB[row * 64 + gp * 8] = pb;
      }
    }
    __syncthreads();
#pragma unroll
    for (int ks = 0; ks < 2; ++ks) {
      bf16x8 af[4], bfr[4];
#pragma unroll
      for (int mr = 0; mr < 4; ++mr) {
        int rr = wr * 64 + mr * 16 + l15;
        af[mr] = *(bf16x8*)&sA[rr * 64 + ((ks * 4 + l4) ^ (rr & 7)) * 8];
      }
#pragma unroll
      for (int nr = 0; nr < 4; ++nr) {
        int rr = wc * 64 + nr * 16 + l15;
        bfr[nr] = *(bf16x8*)&sB[rr * 64 + ((ks * 4 + l4) ^ (rr & 7)) * 8];
      }
#pragma unroll
      for (int mr = 0; mr < 4; ++mr)
#pragma unroll
        for (int nr = 0; nr < 4; ++nr)
          acc[mr][nr] = __builtin_amdgcn_mfma_f32_16x16x32_bf16(af[mr], bfr[nr],
                                                                acc[mr][nr], 0, 0, 0);
    }
  }
#pragma unroll
  for (int nr = 0; nr < 4; ++nr) {
    int nn = n0 + wc * 64 + nr * 16 + l15;
    int which = nn >> 9, co = nn & 511;
    int head = co >> 6, d = co & 63;
    u16* dst = (which == 0) ? Q : (which == 1) ? K : V;
    float sc = (which == 0) ? 0.125f : 1.f;
#pragma unroll
    for (int mr = 0; mr < 4; ++mr) {
      int mb = m0 + wr * 64 + mr * 16 + l4 * 4;
#pragma unroll
      for (int r = 0; r < 4; ++r) {
        int m = mb + r;
        int bb = m >> 10, ii = m & 1023;
        dst[((((size_t)bb * 8 + head) << 10) + ii) * 64 + d] =
            f2bf(acc[mr][nr][r] * sc);
      }
    }
  }
}

// ---------- Kernel 2: S = Q @ K^T per (b,h), bf16 MFMA, out fp8 ----------
__global__ __launch_bounds__(256) void k_qk(const u16* __restrict__ Q,
                                            const u16* __restrict__ Kp,
                                            unsigned char* __restrict__ S8) {
  const int bh = blockIdx.z;
  const u16* Qb = Q + (size_t)bh * 65536;
  const u16* Kb = Kp + (size_t)bh * 65536;
  __shared__ __align__(16) u16 sQ[128 * 64];
  __shared__ __align__(16) u16 sK[128 * 64];
  const int tid = threadIdx.x;
  const int m0 = blockIdx.x * 128, n0 = blockIdx.y * 128;
  {
    int row = tid >> 1, half = tid & 1;
    const u16* gq = &Qb[(size_t)(m0 + row) * 64 + half * 32];
    const u16* gk = &Kb[(size_t)(n0 + row) * 64 + half * 32];
    int xr = row & 7;
#pragma unroll
    for (int q = 0; q < 4; ++q) {
      int gp = (half * 4 + q) ^ xr;
      *(uint4*)&sQ[row * 64 + gp * 8] = *(const uint4*)&gq[q * 8];
      *(uint4*)&sK[row * 64 + gp * 8] = *(const uint4*)&gk[q * 8];
    }
  }
  __syncthreads();
  const int lane = tid & 63, wid = tid >> 6;
  const int wr = wid >> 1, wc = wid & 1;
  const int l15 = lane & 15, l4 = lane >> 4;
  f32x4 acc[4][4] = {};
  bf16x8 af[4][2], bf[4][2];
#pragma unroll
  for (int mr = 0; mr < 4; ++mr) {
    int row = wr * 64 + mr * 16 + l15;
#pragma unroll
    for (int ks = 0; ks < 2; ++ks)
      af[mr][ks] = *(bf16x8*)&sQ[row * 64 + ((ks * 4 + l4) ^ (row & 7)) * 8];
  }
#pragma unroll
  for (int nr = 0; nr < 4; ++nr) {
    int row = wc * 64 + nr * 16 + l15;
#pragma unroll
    for (int ks = 0; ks < 2; ++ks)
      bf[nr][ks] = *(bf16x8*)&sK[row * 64 + ((ks * 4 + l4) ^ (row & 7)) * 8];
  }
#pragma unroll
  for (int mr = 0; mr < 4; ++mr)
#pragma unroll
    for (int nr = 0; nr < 4; ++nr)
#pragma unroll
      for (int ks = 0; ks < 2; ++ks)
        acc[mr][nr] = __builtin_amdgcn_mfma_f32_16x16x32_bf16(af[mr][ks], bf[nr][ks],
                                                              acc[mr][nr], 0, 0, 0);
  __syncthreads();
  unsigned char* t8 = (unsigned char*)sQ;  // reuse 16KB as fp8 [128][128]
#pragma unroll
  for (int mr = 0; mr < 4; ++mr) {
    int mloc = wr * 64 + mr * 16 + l4 * 4;
#pragma unroll
    for (int nr = 0; nr < 4; ++nr) {
      int nloc = wc * 64 + nr * 16 + l15;
#pragma unroll
      for (int r = 0; r < 4; ++r)
        t8[(mloc + r) * 128 + nloc] = f2fp8(acc[mr][nr][r]);
    }
  }
  __syncthreads();
  {
    int row = tid >> 1, c0 = (tid & 1) * 64;
    unsigned char* dst = &S8[((size_t)bh << 20) + (size_t)(m0 + row) * 1024 + n0 + c0];
#pragma unroll
    for (int q = 0; q < 4; ++q)
      *(uint4*)&dst[q * 16] = *(uint4*)&t8[row * 128 + c0 + q * 16];
  }
}

// ---------- Kernel 3: conv3x3(heads)+BN+sigmoid+exp, all-fp8 MFMA GEMM ----------
// Block per (b, row-pair). M=16 = (p in {0,1}) x (oh in 0..7).
// Per tap: one fp8 MFMA with K=32 (k = ih*4 + rr).
// Staging: per-lane byte columns (conflict-free); P via LDS then coalesced.
__global__ __launch_bounds__(256) void k_conv(
    const unsigned char* __restrict__ S8, unsigned char* __restrict__ P8,
    float* __restrict__ D, const float* __restrict__ cw,
    const float* __restrict__ cb, const float* __restrict__ bg,
    const float* __restrict__ bb, const float* __restrict__ bm,
    const float* __restrict__ bv) {
  const int b = blockIdx.x >> 9, ip = blockIdx.x & 511;
  const int i0 = ip * 2;
  __shared__ __align__(16) unsigned char sC[1026 * 40];  // [ci][k], 40B pitch
  __shared__ __align__(8) unsigned char sA[3][16][40];   // A-frags per tap, fp8
  __shared__ __align__(16) unsigned char sP[16 * 1040];  // P out staging
  __shared__ float sRedD[4][16];
  const int tid = threadIdx.x;
  const int lane = tid & 63, wid = tid >> 6;
  const int l15 = lane & 15, l4 = lane >> 4;

  // Build A fp8 (weights folded with BN scale). 1536 entries.
  for (int u = tid; u < 1536; u += 256) {
    int tap = u >> 9, rem = u & 511;
    int m = rem >> 5, kk = rem & 31;
    int p = m >> 3, oh = m & 7;
    int ih = kk >> 2, rr = kk & 3;
    int dr = rr - p;
    float v = 0.f;
    if (dr >= 0 && dr < 3) {
      float ah = bg[oh] * rsqrtf(bv[oh] + 1e-5f);
      v = cw[((oh * 8 + ih) * 3 + dr) * 3 + tap] * ah;
    }
    sA[tap][m][kk] = f2fp8(v);
  }
  // Zero halo cols ci=0 (input col -1) and ci=1025 (input col 1024).
  if (tid < 20) {
    int c = (tid < 10) ? 0 : 1025;
    ((u32*)&sC[c * 40])[tid % 10] = 0;
  }
  // Stage S col-major: each lane owns ONE column per iteration -> ci stride 1
  // across lanes -> word stride 10 (gcd(10,32)=2, 2-way = free).
  {
    const int ihg = tid >> 5, lc = tid & 31;
    const unsigned char* Sb = S8 + (((size_t)(b * 8 + ihg)) << 20);
    const unsigned char* p0 = Sb + (size_t)(i0 - 1) * 1024;
    const bool v0 = (i0 >= 1), v3 = (i0 + 2 < 1024);
#pragma unroll 4
    for (int it = 0; it < 32; ++it) {
      int c = lc + it * 32;
      u32 b0 = v0 ? (u32)p0[c] : 0u;
      u32 b1 = (u32)p0[c + 1024];
      u32 b2 = (u32)p0[c + 2048];
      u32 b3 = v3 ? (u32)p0[c + 3072] : 0u;
      *(u32*)&sC[(c + 1) * 40 + ihg * 4] = b0 | (b1 << 8) | (b2 << 16) | (b3 << 24);
    }
  }
  __syncthreads();

  // A fragments (3 taps) + per-lane epilogue constants.
  long afr[3];
#pragma unroll
  for (int tap = 0; tap < 3; ++tap)
    afr[tap] = *(long*)&sA[tap][l15][l4 * 8];
  float bias2[4];
#pragma unroll
  for (int r = 0; r < 4; ++r) {
    int m = l4 * 4 + r, oh = m & 7;
    float ah = bg[oh] * rsqrtf(bv[oh] + 1e-5f);
    bias2[r] = cb[oh] * ah + bb[oh] - bm[oh] * ah;
  }
  float dsum[4] = {0.f, 0.f, 0.f, 0.f};

  const int jw = wid * 256;
  for (int t = 0; t < 16; ++t) {
    int j = jw + t * 16;
    f32x4 acc = {0.f, 0.f, 0.f, 0.f};
#pragma unroll
    for (int tap = 0; tap < 3; ++tap) {
      long bfrag = *(long*)&sC[(size_t)(j + l15 + tap) * 40 + l4 * 8];
      acc = __builtin_amdgcn_mfma_f32_16x16x32_fp8_fp8(afr[tap], bfrag, acc, 0, 0, 0);
    }
#pragma unroll
    for (int r = 0; r < 4; ++r) {
      int m = l4 * 4 + r;
      float tt = acc[r] + bias2[r];
      float sg = 1.f / (1.f + __expf(-tt));
      float e = __expf(sg);
      unsigned char q8 = f2fp8(e);
      sP[m * 1040 + j + l15] = q8;
      dsum[r] += up2_lo((u32)q8).x;  // quantized numerator for exact norm
    }
  }
#pragma unroll
  for (int r = 0; r < 4; ++r) {
#pragma unroll
    for (int msk = 8; msk >= 1; msk >>= 1) dsum[r] += __shfl_xor(dsum[r], msk);
  }
  if (l15 == 0) {
#pragma unroll
    for (int r = 0; r < 4; ++r) sRedD[wid][l4 * 4 + r] = dsum[r];
  }
  __syncthreads();
  if (tid < 16) {
    int p = tid >> 3, oh = tid & 7;
    D[((size_t)(b * 8 + oh) << 10) + i0 + p] =
        sRedD[0][tid] + sRedD[1][tid] + sRedD[2][tid] + sRedD[3][tid];
  }
  // Coalesced P8 store: thread -> (m = tid & 15, 64B chunk = tid >> 4).
  {
    const int m = tid & 15, ch = tid >> 4;
    const int p = m >> 3, oh = m & 7;
    unsigned char* dst =
        &P8[((size_t)(b * 8 + oh) << 20) + ((size_t)(i0 + p) << 10) + ch * 64];
    const unsigned char* src = &sP[m * 1040 + ch * 64];
#pragma unroll
    for (int q = 0; q < 4; ++q)
      *(uint4*)&dst[q * 16] = *(const uint4*)&src[q * 16];
  }
}

// ---------- Kernel 4: Z = (P @ V) / D per (b,h), fp8 MFMA ----------
__global__ __launch_bounds__(256) void k_av(const unsigned char* __restrict__ P8,
                                            const u16* __restrict__ V,
                                            const float* __restrict__ D,
                                            u16* __restrict__ Z) {
  const int bh = blockIdx.y, m0 = blockIdx.x * 128;
  const int b = bh >> 3, h = bh & 7;
  __shared__ __align__(16) unsigned char sA8[128 * 64];
  __shared__ __align__(16) unsigned char sVt[64 * 64];
  const int tid = threadIdx.x, lane = tid & 63, wid = tid >> 6;
  const int wr = wid >> 1, wc = wid & 1, l15 = lane & 15, l4 = lane >> 4;
  f32x4 acc[4][2] = {};
  for (int k0 = 0; k0 < 1024; k0 += 64) {
    __syncthreads();
    {  // stage A (P fp8), swizzled
      int row = tid >> 1, c0 = (tid & 1) * 32;
      const unsigned char* src =
          &P8[((size_t)bh << 20) + (size_t)(m0 + row) * 1024 + k0 + c0];
      uint4 a0 = *(const uint4*)src, a1 = *(const uint4*)(src + 16);
      u64 ul[4];
      ul[0] = (u64)a0.x | ((u64)a0.y << 32);
      ul[1] = (u64)a0.z | ((u64)a0.w << 32);
      ul[2] = (u64)a1.x | ((u64)a1.y << 32);
      ul[3] = (u64)a1.z | ((u64)a1.w << 32);
      int xr = row & 7, gb = c0 >> 3;
#pragma unroll
      for (int t = 0; t < 4; ++t)
        *(u64*)&sA8[row * 64 + ((gb + t) ^ xr) * 8] = ul[t];
    }
    {  // stage V^T as fp8, swizzled
      int j = tid >> 2, d0 = (tid & 3) * 16;
      const u16* src = &V[((size_t)bh << 16) + (size_t)(k0 + j) * 64 + d0];
      uint4 v0 = *(const uint4*)src, v1 = *(const uint4*)(src + 16);
      u32 wv[8] = {v0.x, v0.y, v0.z, v0.w, v1.x, v1.y, v1.z, v1.w};
#pragma unroll
      for (int t = 0; t < 8; ++t) {
        u32 p = (u32)__builtin_amdgcn_cvt_pk_fp8_f32(bflo(wv[t]), bfhi(wv[t]), 0, false);
        int da = d0 + t * 2, db = da + 1;
        sVt[da * 64 + (((j >> 3) ^ (da & 7)) << 3) + (j & 7)] = (unsigned char)(p & 0xff);
        sVt[db * 64 + (((j >> 3) ^ (db & 7)) << 3) + (j & 7)] = (unsigned char)((p >> 8) & 0xff);
      }
    }
    __syncthreads();
    long bfr[2][2];
#pragma unroll
    for (int nr = 0; nr < 2; ++nr) {
      int row = wc * 32 + nr * 16 + l15;
#pragma unroll
      for (int ks = 0; ks < 2; ++ks)
        bfr[nr][ks] = *(long*)&sVt[row * 64 + (((ks * 4 + l4) ^ (row & 7)) << 3)];
    }
#pragma unroll
    for (int mr = 0; mr < 4; ++mr) {
      int row = wr * 64 + mr * 16 + l15;
      long afr[2];
#pragma unroll
      for (int ks = 0; ks < 2; ++ks)
        afr[ks] = *(long*)&sA8[row * 64 + (((ks * 4 + l4) ^ (row & 7)) << 3)];
#pragma unroll
      for (int nr = 0; nr < 2; ++nr)
#pragma unroll
        for (int ks = 0; ks < 2; ++ks)
          acc[mr][nr] = __builtin_amdgcn_mfma_f32_16x16x32_fp8_fp8(afr[ks], bfr[nr][ks],
                                                                   acc[mr][nr], 0, 0, 0);
    }
  }
#pragma unroll
  for (int mr = 0; mr < 4; ++mr) {
    int mbase = m0 + wr * 64 + mr * 16 + l4 * 4;
    float dv[4];
#pragma unroll
    for (int r = 0; r < 4; ++r) dv[r] = 1.f / D[((size_t)bh << 10) + mbase + r];
#pragma unroll
    for (int nr = 0; nr < 2; ++nr) {
      int d = wc * 32 + nr * 16 + l15;
#pragma unroll
      for (int r = 0; r < 4; ++r)
        Z[((size_t)(b * 1024 + mbase + r)) * 512 + h * 64 + d] =
            f2bf(acc[mr][nr][r] * dv[r]);
    }
  }
}

// ---------- Kernel 5: out = Z @ W^T + b + x, bf16 MFMA. M=8192,N=512,K=512 ----------
__global__ __launch_bounds__(256) void k_proj(const u16* __restrict__ Z,
                                              const float* __restrict__ w,
                                              const float* __restrict__ bias,
                                              const float* __restrict__ xin,
                                              float* __restrict__ out) {
  __shared__ __align__(16) u16 sA[128 * 64];
  __shared__ __align__(16) u16 sB[128 * 64];
  const int tid = threadIdx.x;
  const int m0 = blockIdx.x * 128, n0 = blockIdx.y * 128;
  const int lane = tid & 63, wid = tid >> 6;
  const int wr = wid >> 1, wc = wid & 1;
  const int l15 = lane & 15, l4 = lane >> 4;
  const int row = tid >> 1, half = tid & 1, xr = row & 7;
  f32x4 acc[4][4] = {};
  for (int k0 = 0; k0 < 512; k0 += 64) {
    __syncthreads();
    {
      const u16* gz = &Z[(size_t)(m0 + row) * 512 + k0 + half * 32];
      const float* gb = &w[(size_t)(n0 + row) * 512 + k0 + half * 32];
#pragma unroll
      for (int q = 0; q < 4; ++q) {
        int gp = (half * 4 + q) ^ xr;
        *(uint4*)&sA[row * 64 + gp * 8] = *(const uint4*)&gz[q * 8];
        float4 b0 = *(const float4*)&gb[q * 8];
        float4 b1 = *(const float4*)&gb[q * 8 + 4];
        uint4 pb;
        pb.x = cvtpk_bf16(b0.x, b0.y); pb.y = cvtpk_bf16(b0.z, b0.w);
        pb.z = cvtpk_bf16(b1.x, b1.y); pb.w = cvtpk_bf16(b1.z, b1.w);
        *(uint4*)&sB[row * 64 + gp * 8] = pb;
      }
    }
    __syncthreads();
#pragma unroll
    for (int ks = 0; ks < 2; ++ks) {
      bf16x8 af[4], bfr[4];
#pragma unroll
      for (int mr = 0; mr < 4; ++mr) {
        int rr = wr * 64 + mr * 16 + l15;
        af[mr] = *(bf16x8*)&sA[rr * 64 + ((ks * 4 + l4) ^ (rr & 7)) * 8];
      }
#pragma unroll
      for (int nr = 0; nr < 4; ++nr) {
        int rr = wc * 64 + nr * 16 + l15;
        bfr[nr] = *(bf16x8*)&sB[rr * 64 + ((ks * 4 + l4) ^ (rr & 7)) * 8];
      }
#pragma unroll
      for (int mr = 0; mr < 4; ++mr)
#pragma unroll
        for (int nr = 0; nr < 4; ++nr)
          acc[mr][nr] = __builtin_amdgcn_mfma_f32_16x16x32_bf16(af[mr], bfr[nr],
                                                                acc[mr][nr], 0, 0, 0);
    }
  }
#pragma unroll
  for (int nr = 0; nr < 4; ++nr) {
    int nn = n0 + wc * 64 + nr * 16 + l15;
    float bv2 = bias[nn];
#pragma unroll
    for (int mr = 0; mr < 4; ++mr) {
      int mb = m0 + wr * 64 + mr * 16 + l4 * 4;
#pragma unroll
      for (int r = 0; r < 4; ++r) {
        size_t o = (size_t)(mb + r) * 512 + nn;
        out[o] = acc[mr][nr][r] + bv2 + xin[o];
      }
    }
  }
}

extern "C" void kernel_launch(void* const* d_in, const int* in_sizes, int n_in,
                              void* d_out, int out_size, void* d_ws, size_t ws_size,
                              hipStream_t stream) {
  const size_t need = 160ull << 20;
  if (ws_size < need) return;  // clean diagnostic failure instead of GPU fault

  const float* x      = (const float*)d_in[0];
  const float* qkv_w  = (const float*)d_in[1];
  const float* proj_w = (const float*)d_in[2];
  const float* proj_b = (const float*)d_in[3];
  const float* conv_w = (const float*)d_in[4];
  const float* conv_b = (const float*)d_in[5];
  const float* bn_g   = (const float*)d_in[6];
  const float* bn_b   = (const float*)d_in[7];
  const float* bn_m   = (const float*)d_in[8];
  const float* bn_v   = (const float*)d_in[9];
  float* out = (float*)d_out;

  char* W = (char*)d_ws;
  u16* Wq = (u16*)W;                       // Q bf16 8MB; dead after k_qk
  float* Dbuf = (float*)W;                 // D f32 256KB, overlays Q region
  u16* Wk = (u16*)(W + (8ull << 20));
  u16* Wv = (u16*)(W + (16ull << 20));
  u16* Wz = (u16*)(W + (24ull << 20));
  unsigned char* S8 = (unsigned char*)(W + (32ull << 20));  // 64MB
  unsigned char* P8 = (unsigned char*)(W + (96ull << 20));  // 64MB

  k_qkv<<<dim3(64, 12), 256, 0, stream>>>(x, qkv_w, Wq, Wk, Wv);
  k_qk<<<dim3(8, 8, 64), 256, 0, stream>>>(Wq, Wk, S8);
  k_conv<<<dim3(4096), 256, 0, stream>>>(S8, P8, Dbuf, conv_w, conv_b, bn_g, bn_b,
                                         bn_m, bn_v);
  k_av<<<dim3(8, 64), 256, 0, stream>>>(P8, Wv, Dbuf, Wz);
  k_proj<<<dim3(64, 4), 256, 0, stream>>>(Wz, proj_w, proj_b, x, out);
}

// Round 12
// 215.002 us; speedup vs baseline: 1.2628x; 1.2628x over previous
//
#include <hip/hip_runtime.h>

// GuidedAttention on MI355X, round 12: resubmission of round 11 (infra
// failure on a dead container — code never ran). Round-9 base (219us) with
// k_conv GEMM transposed (operand swap -> C[j][m]) so the epilogue packs 4
// consecutive j per lane into ONE u32 store (was 4 scattered byte stores),
// P8 row base hoisted per-lane. Staging identical to round-9 u32 loads.
// b=8, n=1024, c=512, H=8, hd=64.
// ws layout (160 MB): [Q bf16 8MB | D f32 256KB overlaid after k_qk]
//                     [K bf16 8MB][V bf16 8MB][Z bf16 8MB]
//                     [S fp8 64MB][P fp8 64MB]

#define DINL __device__ __forceinline__
typedef unsigned short u16;
typedef unsigned int u32;
typedef unsigned long long u64;
typedef short bf16x8 __attribute__((ext_vector_type(8)));
typedef float f32x4 __attribute__((ext_vector_type(4)));
typedef float f32x2 __attribute__((ext_vector_type(2)));

DINL u16 f2bf(float f) {
  u32 u = __float_as_uint(f);
  u += 0x7fffu + ((u >> 16) & 1u);
  return (u16)(u >> 16);
}
DINL float bflo(u32 u) { return __uint_as_float(u << 16); }
DINL float bfhi(u32 u) { return __uint_as_float(u & 0xffff0000u); }
DINL u32 cvtpk_bf16(float lo, float hi) {
  u32 r;
  asm("v_cvt_pk_bf16_f32 %0, %1, %2" : "=v"(r) : "v"(lo), "v"(hi));
  return r;
}
DINL u32 pk4_fp8(float a, float b, float c, float d) {
  u32 r = 0;
  r = (u32)__builtin_amdgcn_cvt_pk_fp8_f32(a, b, (int)r, false);
  r = (u32)__builtin_amdgcn_cvt_pk_fp8_f32(c, d, (int)r, true);
  return r;
}
DINL f32x2 up2_lo(u32 w) { return __builtin_amdgcn_cvt_pk_f32_fp8((int)w, false); }
DINL f32x2 up2_hi(u32 w) { return __builtin_amdgcn_cvt_pk_f32_fp8((int)w, true); }
DINL unsigned char f2fp8(float v) {
  return (unsigned char)((u32)__builtin_amdgcn_cvt_pk_fp8_f32(v, v, 0, false) & 0xffu);
}

// ---------- Kernel 1: QKV proj, bf16 MFMA. M=8192, N=1536, K=512 ----------
__global__ __launch_bounds__(256) void k_qkv(const float* __restrict__ x,
                                             const float* __restrict__ w,
                                             u16* __restrict__ Q,
                                             u16* __restrict__ K,
                                             u16* __restrict__ V) {
  __shared__ __align__(16) u16 sA[128 * 64];
  __shared__ __align__(16) u16 sB[128 * 64];
  const int tid = threadIdx.x;
  const int m0 = blockIdx.x * 128, n0 = blockIdx.y * 128;
  const int lane = tid & 63, wid = tid >> 6;
  const int wr = wid >> 1, wc = wid & 1;
  const int l15 = lane & 15, l4 = lane >> 4;
  const int row = tid >> 1, half = tid & 1, xr = row & 7;
  f32x4 acc[4][4] = {};
  for (int k0 = 0; k0 < 512; k0 += 64) {
    __syncthreads();
    {
      const float* ga = &x[(size_t)(m0 + row) * 512 + k0 + half * 32];
      const float* gb = &w[(size_t)(n0 + row) * 512 + k0 + half * 32];
#pragma unroll
      for (int q = 0; q < 4; ++q) {
        int gp = (half * 4 + q) ^ xr;
        float4 a0 = *(const float4*)&ga[q * 8];
        float4 a1 = *(const float4*)&ga[q * 8 + 4];
        uint4 pa;
        pa.x = cvtpk_bf16(a0.x, a0.y); pa.y = cvtpk_bf16(a0.z, a0.w);
        pa.z = cvtpk_bf16(a1.x, a1.y); pa.w = cvtpk_bf16(a1.z, a1.w);
        *(uint4*)&sA[row * 64 + gp * 8] = pa;
        float4 b0 = *(const float4*)&gb[q * 8];
        float4 b1 = *(const float4*)&gb[q * 8 + 4];
        uint4 pb;
        pb.x = cvtpk_bf16(b0.x, b0.y); pb.y = cvtpk_bf16(b0.z, b0.w);
        pb.z = cvtpk_bf16(b1.x, b1.y); pb.w = cvtpk_bf16(b1.z, b1.w);
        *(uint4*)&sB[row * 64 + gp * 8] = pb;
      }
    }
    __syncthreads();
#pragma unroll
    for (int ks = 0; ks < 2; ++ks) {
      bf16x8 af[4], bfr[4];
#pragma unroll
      for (int mr = 0; mr < 4; ++mr) {
        int rr = wr * 64 + mr * 16 + l15;
        af[mr] = *(bf16x8*)&sA[rr * 64 + ((ks * 4 + l4) ^ (rr & 7)) * 8];
      }
#pragma unroll
      for (int nr = 0; nr < 4; ++nr) {
        int rr = wc * 64 + nr * 16 + l15;
        bfr[nr] = *(bf16x8*)&sB[rr * 64 + ((ks * 4 + l4) ^ (rr & 7)) * 8];
      }
#pragma unroll
      for (int mr = 0; mr < 4; ++mr)
#pragma unroll
        for (int nr = 0; nr < 4; ++nr)
          acc[mr][nr] = __builtin_amdgcn_mfma_f32_16x16x32_bf16(af[mr], bfr[nr],
                                                                acc[mr][nr], 0, 0, 0);
    }
  }
#pragma unroll
  for (int nr = 0; nr < 4; ++nr) {
    int nn = n0 + wc * 64 + nr * 16 + l15;
    int which = nn >> 9, co = nn & 511;
    int head = co >> 6, d = co & 63;
    u16* dst = (which == 0) ? Q : (which == 1) ? K : V;
    float sc = (which == 0) ? 0.125f : 1.f;
#pragma unroll
    for (int mr = 0; mr < 4; ++mr) {
      int mb = m0 + wr * 64 + mr * 16 + l4 * 4;
#pragma unroll
      for (int r = 0; r < 4; ++r) {
        int m = mb + r;
        int bb = m >> 10, ii = m & 1023;
        dst[((((size_t)bb * 8 + head) << 10) + ii) * 64 + d] =
            f2bf(acc[mr][nr][r] * sc);
      }
    }
  }
}

// ---------- Kernel 2: S = Q @ K^T per (b,h), bf16 MFMA, out fp8 ----------
__global__ __launch_bounds__(256) void k_qk(const u16* __restrict__ Q,
                                            const u16* __restrict__ Kp,
                                            unsigned char* __restrict__ S8) {
  const int bh = blockIdx.z;
  const u16* Qb = Q + (size_t)bh * 65536;
  const u16* Kb = Kp + (size_t)bh * 65536;
  __shared__ __align__(16) u16 sQ[128 * 64];
  __shared__ __align__(16) u16 sK[128 * 64];
  const int tid = threadIdx.x;
  const int m0 = blockIdx.x * 128, n0 = blockIdx.y * 128;
  {
    int row = tid >> 1, half = tid & 1;
    const u16* gq = &Qb[(size_t)(m0 + row) * 64 + half * 32];
    const u16* gk = &Kb[(size_t)(n0 + row) * 64 + half * 32];
    int xr = row & 7;
#pragma unroll
    for (int q = 0; q < 4; ++q) {
      int gp = (half * 4 + q) ^ xr;
      *(uint4*)&sQ[row * 64 + gp * 8] = *(const uint4*)&gq[q * 8];
      *(uint4*)&sK[row * 64 + gp * 8] = *(const uint4*)&gk[q * 8];
    }
  }
  __syncthreads();
  const int lane = tid & 63, wid = tid >> 6;
  const int wr = wid >> 1, wc = wid & 1;
  const int l15 = lane & 15, l4 = lane >> 4;
  f32x4 acc[4][4] = {};
  bf16x8 af[4][2], bf[4][2];
#pragma unroll
  for (int mr = 0; mr < 4; ++mr) {
    int row = wr * 64 + mr * 16 + l15;
#pragma unroll
    for (int ks = 0; ks < 2; ++ks)
      af[mr][ks] = *(bf16x8*)&sQ[row * 64 + ((ks * 4 + l4) ^ (row & 7)) * 8];
  }
#pragma unroll
  for (int nr = 0; nr < 4; ++nr) {
    int row = wc * 64 + nr * 16 + l15;
#pragma unroll
    for (int ks = 0; ks < 2; ++ks)
      bf[nr][ks] = *(bf16x8*)&sK[row * 64 + ((ks * 4 + l4) ^ (row & 7)) * 8];
  }
#pragma unroll
  for (int mr = 0; mr < 4; ++mr)
#pragma unroll
    for (int nr = 0; nr < 4; ++nr)
#pragma unroll
      for (int ks = 0; ks < 2; ++ks)
        acc[mr][nr] = __builtin_amdgcn_mfma_f32_16x16x32_bf16(af[mr][ks], bf[nr][ks],
                                                              acc[mr][nr], 0, 0, 0);
  __syncthreads();
  unsigned char* t8 = (unsigned char*)sQ;  // reuse 16KB as fp8 [128][128]
#pragma unroll
  for (int mr = 0; mr < 4; ++mr) {
    int mloc = wr * 64 + mr * 16 + l4 * 4;
#pragma unroll
    for (int nr = 0; nr < 4; ++nr) {
      int nloc = wc * 64 + nr * 16 + l15;
#pragma unroll
      for (int r = 0; r < 4; ++r)
        t8[(mloc + r) * 128 + nloc] = f2fp8(acc[mr][nr][r]);
    }
  }
  __syncthreads();
  {
    int row = tid >> 1, c0 = (tid & 1) * 64;
    unsigned char* dst = &S8[((size_t)bh << 20) + (size_t)(m0 + row) * 1024 + n0 + c0];
#pragma unroll
    for (int q = 0; q < 4; ++q)
      *(uint4*)&dst[q * 16] = *(uint4*)&t8[row * 128 + c0 + q * 16];
  }
}

// ---------- Kernel 3: conv3x3(heads)+BN+sigmoid+exp, all-fp8 MFMA GEMM ----------
// Block per (b, row-pair). TRANSPOSED output C[j][m]: per tap,
// mfma(A = S-columns [j rows x K=32], B = weights [K=32 x m cols]).
// Lane: m = l15 (fixed), j = jbase + l4*4 + r -> 4 consecutive j -> 1 u32 store.
__global__ __launch_bounds__(256) void k_conv(
    const unsigned char* __restrict__ S8, unsigned char* __restrict__ P8,
    float* __restrict__ D, const float* __restrict__ cw,
    const float* __restrict__ cb, const float* __restrict__ bg,
    const float* __restrict__ bb, const float* __restrict__ bm,
    const float* __restrict__ bv) {
  const int b = blockIdx.x >> 9, ip = blockIdx.x & 511;
  const int i0 = ip * 2;
  __shared__ __align__(16) unsigned char sC[1026 * 40];  // [ci][k], 40B pitch
  __shared__ __align__(8) unsigned char sA[3][16][40];   // weights per tap, fp8
  __shared__ float sRedD[4][16];
  const int tid = threadIdx.x;
  const int lane = tid & 63, wid = tid >> 6;
  const int l15 = lane & 15, l4 = lane >> 4;

  // Build weight matrix fp8 (folded with BN scale). 1536 entries.
  for (int u = tid; u < 1536; u += 256) {
    int tap = u >> 9, rem = u & 511;
    int m = rem >> 5, kk = rem & 31;
    int p = m >> 3, oh = m & 7;
    int ih = kk >> 2, rr = kk & 3;
    int dr = rr - p;
    float v = 0.f;
    if (dr >= 0 && dr < 3) {
      float ah = bg[oh] * rsqrtf(bv[oh] + 1e-5f);
      v = cw[((oh * 8 + ih) * 3 + dr) * 3 + tap] * ah;
    }
    sA[tap][m][kk] = f2fp8(v);
  }
  // Zero halo cols ci=0 (input col -1) and ci=1025 (input col 1024).
  if (tid < 20) {
    int c = (tid < 10) ? 0 : 1025;
    ((u32*)&sC[c * 40])[tid % 10] = 0;
  }
  // Stage S col-major: u32 loads + in-lane 4x4 byte transpose (round-9).
  {
    const int ihs = tid >> 5;  // 0..7
    const int lc = tid & 31;
    const unsigned char* Sb = S8 + (((size_t)(b * 8 + ihs)) << 20);
    for (int it = 0; it < 8; ++it) {
      int c0 = (lc + it * 32) * 4;
      u32 w[4];
#pragma unroll
      for (int rr = 0; rr < 4; ++rr) {
        int r = i0 - 1 + rr;
        w[rr] = (r >= 0 && r < 1024) ? *(const u32*)&Sb[(size_t)r * 1024 + c0] : 0u;
      }
#pragma unroll
      for (int cc = 0; cc < 4; ++cc) {
        u32 v = ((w[0] >> (8 * cc)) & 0xffu) | (((w[1] >> (8 * cc)) & 0xffu) << 8) |
                (((w[2] >> (8 * cc)) & 0xffu) << 16) |
                (((w[3] >> (8 * cc)) & 0xffu) << 24);
        *(u32*)&sC[(c0 + cc + 1) * 40 + ihs * 4] = v;
      }
    }
  }
  __syncthreads();

  // Weight fragments (3 taps) as the B operand; per-lane output-row constants.
  long wfr[3];
#pragma unroll
  for (int tap = 0; tap < 3; ++tap)
    wfr[tap] = *(long*)&sA[tap][l15][l4 * 8];
  const int oh = l15 & 7, p = l15 >> 3;
  const float ah = bg[oh] * rsqrtf(bv[oh] + 1e-5f);
  const float biasm = cb[oh] * ah + bb[oh] - bm[oh] * ah;
  unsigned char* Prow = &P8[((size_t)(b * 8 + oh) << 20) + ((size_t)(i0 + p) << 10)];
  float dsum = 0.f;

  const int jw = wid * 256;
  for (int t = 0; t < 16; ++t) {
    int jbase = jw + t * 16;
    f32x4 acc = {0.f, 0.f, 0.f, 0.f};
#pragma unroll
    for (int tap = 0; tap < 3; ++tap) {
      long sfr = *(long*)&sC[(size_t)(jbase + l15 + tap) * 40 + l4 * 8];
      acc = __builtin_amdgcn_mfma_f32_16x16x32_fp8_fp8(sfr, wfr[tap], acc, 0, 0, 0);
    }
    float e[4];
#pragma unroll
    for (int r = 0; r < 4; ++r) {
      float tt = acc[r] + biasm;
      float sg = 1.f / (1.f + __expf(-tt));
      e[r] = __expf(sg);  // softmax numerator; sg in (0,1) so no max needed
    }
    u32 pw = pk4_fp8(e[0], e[1], e[2], e[3]);
    *(u32*)&Prow[jbase + l4 * 4] = pw;
    // denominator from QUANTIZED numerators for exact normalization
    f32x2 dlo = up2_lo(pw), dhi = up2_hi(pw);
    dsum += (dlo.x + dlo.y) + (dhi.x + dhi.y);
  }
  // Reduce across the 4 lanes sharing m=l15 (l4 = lane bits 4-5).
  dsum += __shfl_xor(dsum, 16);
  dsum += __shfl_xor(dsum, 32);
  if (l4 == 0) sRedD[wid][l15] = dsum;
  __syncthreads();
  if (tid < 16) {
    int pp = tid >> 3, ohh = tid & 7;
    D[((size_t)(b * 8 + ohh) << 10) + i0 + pp] =
        sRedD[0][tid] + sRedD[1][tid] + sRedD[2][tid] + sRedD[3][tid];
  }
}

// ---------- Kernel 4: Z = (P @ V) / D per (b,h), fp8 MFMA ----------
__global__ __launch_bounds__(256) void k_av(const unsigned char* __restrict__ P8,
                                            const u16* __restrict__ V,
                                            const float* __restrict__ D,
                                            u16* __restrict__ Z) {
  const int bh = blockIdx.y, m0 = blockIdx.x * 128;
  const int b = bh >> 3, h = bh & 7;
  __shared__ __align__(16) unsigned char sA8[128 * 64];
  __shared__ __align__(16) unsigned char sVt[64 * 64];
  const int tid = threadIdx.x, lane = tid & 63, wid = tid >> 6;
  const int wr = wid >> 1, wc = wid & 1, l15 = lane & 15, l4 = lane >> 4;
  f32x4 acc[4][2] = {};
  for (int k0 = 0; k0 < 1024; k0 += 64) {
    __syncthreads();
    {  // stage A (P fp8), swizzled
      int row = tid >> 1, c0 = (tid & 1) * 32;
      const unsigned char* src =
          &P8[((size_t)bh << 20) + (size_t)(m0 + row) * 1024 + k0 + c0];
      uint4 a0 = *(const uint4*)src, a1 = *(const uint4*)(src + 16);
      u64 ul[4];
      ul[0] = (u64)a0.x | ((u64)a0.y << 32);
      ul[1] = (u64)a0.z | ((u64)a0.w << 32);
      ul[2] = (u64)a1.x | ((u64)a1.y << 32);
      ul[3] = (u64)a1.z | ((u64)a1.w << 32);
      int xr = row & 7, gb = c0 >> 3;
#pragma unroll
      for (int t = 0; t < 4; ++t)
        *(u64*)&sA8[row * 64 + ((gb + t) ^ xr) * 8] = ul[t];
    }
    {  // stage V^T as fp8, swizzled
      int j = tid >> 2, d0 = (tid & 3) * 16;
      const u16* src = &V[((size_t)bh << 16) + (size_t)(k0 + j) * 64 + d0];
      uint4 v0 = *(const uint4*)src, v1 = *(const uint4*)(src + 16);
      u32 wv[8] = {v0.x, v0.y, v0.z, v0.w, v1.x, v1.y, v1.z, v1.w};
#pragma unroll
      for (int t = 0; t < 8; ++t) {
        u32 p = (u32)__builtin_amdgcn_cvt_pk_fp8_f32(bflo(wv[t]), bfhi(wv[t]), 0, false);
        int da = d0 + t * 2, db = da + 1;
        sVt[da * 64 + (((j >> 3) ^ (da & 7)) << 3) + (j & 7)] = (unsigned char)(p & 0xff);
        sVt[db * 64 + (((j >> 3) ^ (db & 7)) << 3) + (j & 7)] = (unsigned char)((p >> 8) & 0xff);
      }
    }
    __syncthreads();
    long bfr[2][2];
#pragma unroll
    for (int nr = 0; nr < 2; ++nr) {
      int row = wc * 32 + nr * 16 + l15;
#pragma unroll
      for (int ks = 0; ks < 2; ++ks)
        bfr[nr][ks] = *(long*)&sVt[row * 64 + (((ks * 4 + l4) ^ (row & 7)) << 3)];
    }
#pragma unroll
    for (int mr = 0; mr < 4; ++mr) {
      int row = wr * 64 + mr * 16 + l15;
      long afr[2];
#pragma unroll
      for (int ks = 0; ks < 2; ++ks)
        afr[ks] = *(long*)&sA8[row * 64 + (((ks * 4 + l4) ^ (row & 7)) << 3)];
#pragma unroll
      for (int nr = 0; nr < 2; ++nr)
#pragma unroll
        for (int ks = 0; ks < 2; ++ks)
          acc[mr][nr] = __builtin_amdgcn_mfma_f32_16x16x32_fp8_fp8(afr[ks], bfr[nr][ks],
                                                                   acc[mr][nr], 0, 0, 0);
    }
  }
#pragma unroll
  for (int mr = 0; mr < 4; ++mr) {
    int mbase = m0 + wr * 64 + mr * 16 + l4 * 4;
    float dv[4];
#pragma unroll
    for (int r = 0; r < 4; ++r) dv[r] = 1.f / D[((size_t)bh << 10) + mbase + r];
#pragma unroll
    for (int nr = 0; nr < 2; ++nr) {
      int d = wc * 32 + nr * 16 + l15;
#pragma unroll
      for (int r = 0; r < 4; ++r)
        Z[((size_t)(b * 1024 + mbase + r)) * 512 + h * 64 + d] =
            f2bf(acc[mr][nr][r] * dv[r]);
    }
  }
}

// ---------- Kernel 5: out = Z @ W^T + b + x, bf16 MFMA. M=8192,N=512,K=512 ----------
__global__ __launch_bounds__(256) void k_proj(const u16* __restrict__ Z,
                                              const float* __restrict__ w,
                                              const float* __restrict__ bias,
                                              const float* __restrict__ xin,
                                              float* __restrict__ out) {
  __shared__ __align__(16) u16 sA[128 * 64];
  __shared__ __align__(16) u16 sB[128 * 64];
  const int tid = threadIdx.x;
  const int m0 = blockIdx.x * 128, n0 = blockIdx.y * 128;
  const int lane = tid & 63, wid = tid >> 6;
  const int wr = wid >> 1, wc = wid & 1;
  const int l15 = lane & 15, l4 = lane >> 4;
  const int row = tid >> 1, half = tid & 1, xr = row & 7;
  f32x4 acc[4][4] = {};
  for (int k0 = 0; k0 < 512; k0 += 64) {
    __syncthreads();
    {
      const u16* gz = &Z[(size_t)(m0 + row) * 512 + k0 + half * 32];
      const float* gb = &w[(size_t)(n0 + row) * 512 + k0 + half * 32];
#pragma unroll
      for (int q = 0; q < 4; ++q) {
        int gp = (half * 4 + q) ^ xr;
        *(uint4*)&sA[row * 64 + gp * 8] = *(const uint4*)&gz[q * 8];
        float4 b0 = *(const float4*)&gb[q * 8];
        float4 b1 = *(const float4*)&gb[q * 8 + 4];
        uint4 pb;
        pb.x = cvtpk_bf16(b0.x, b0.y); pb.y = cvtpk_bf16(b0.z, b0.w);
        pb.z = cvtpk_bf16(b1.x, b1.y); pb.w = cvtpk_bf16(b1.z, b1.w);
        *(uint4*)&sB[row * 64 + gp * 8] = pb;
      }
    }
    __syncthreads();
#pragma unroll
    for (int ks = 0; ks < 2; ++ks) {
      bf16x8 af[4], bfr[4];
#pragma unroll
      for (int mr = 0; mr < 4; ++mr) {
        int rr = wr * 64 + mr * 16 + l15;
        af[mr] = *(bf16x8*)&sA[rr * 64 + ((ks * 4 + l4) ^ (rr & 7)) * 8];
      }
#pragma unroll
      for (int nr = 0; nr < 4; ++nr) {
        int rr = wc * 64 + nr * 16 + l15;
        bfr[nr] = *(bf16x8*)&sB[rr * 64 + ((ks * 4 + l4) ^ (rr & 7)) * 8];
      }
#pragma unroll
      for (int mr = 0; mr < 4; ++mr)
#pragma unroll
        for (int nr = 0; nr < 4; ++nr)
          acc[mr][nr] = __builtin_amdgcn_mfma_f32_16x16x32_bf16(af[mr], bfr[nr],
                                                                acc[mr][nr], 0, 0, 0);
    }
  }
#pragma unroll
  for (int nr = 0; nr < 4; ++nr) {
    int nn = n0 + wc * 64 + nr * 16 + l15;
    float bv2 = bias[nn];
#pragma unroll
    for (int mr = 0; mr < 4; ++mr) {
      int mb = m0 + wr * 64 + mr * 16 + l4 * 4;
#pragma unroll
      for (int r = 0; r < 4; ++r) {
        size_t o = (size_t)(mb + r) * 512 + nn;
        out[o] = acc[mr][nr][r] + bv2 + xin[o];
      }
    }
  }
}

extern "C" void kernel_launch(void* const* d_in, const int* in_sizes, int n_in,
                              void* d_out, int out_size, void* d_ws, size_t ws_size,
                              hipStream_t stream) {
  const size_t need = 160ull << 20;
  if (ws_size < need) return;  // clean diagnostic failure instead of GPU fault

  const float* x      = (const float*)d_in[0];
  const float* qkv_w  = (const float*)d_in[1];
  const float* proj_w = (const float*)d_in[2];
  const float* proj_b = (const float*)d_in[3];
  const float* conv_w = (const float*)d_in[4];
  const float* conv_b = (const float*)d_in[5];
  const float* bn_g   = (const float*)d_in[6];
  const float* bn_b   = (const float*)d_in[7];
  const float* bn_m   = (const float*)d_in[8];
  const float* bn_v   = (const float*)d_in[9];
  float* out = (float*)d_out;

  char* W = (char*)d_ws;
  u16* Wq = (u16*)W;                       // Q bf16 8MB; dead after k_qk
  float* Dbuf = (float*)W;                 // D f32 256KB, overlays Q region
  u16* Wk = (u16*)(W + (8ull << 20));
  u16* Wv = (u16*)(W + (16ull << 20));
  u16* Wz = (u16*)(W + (24ull << 20));
  unsigned char* S8 = (unsigned char*)(W + (32ull << 20));  // 64MB
  unsigned char* P8 = (unsigned char*)(W + (96ull << 20));  // 64MB

  k_qkv<<<dim3(64, 12), 256, 0, stream>>>(x, qkv_w, Wq, Wk, Wv);
  k_qk<<<dim3(8, 8, 64), 256, 0, stream>>>(Wq, Wk, S8);
  k_conv<<<dim3(4096), 256, 0, stream>>>(S8, P8, Dbuf, conv_w, conv_b, bn_g, bn_b,
                                         bn_m, bn_v);
  k_av<<<dim3(8, 64), 256, 0, stream>>>(P8, Wv, Dbuf, Wz);
  k_proj<<<dim3(64, 4), 256, 0, stream>>>(Wz, proj_w, proj_b, x, out);
}